// Round 6
// baseline (164.965 us; speedup 1.0000x reference)
//
#include <hip/hip_runtime.h>

#define HH 512
#define WW 512
#define NBATCH 16
#define NBINS 512   // 511 real shells + 1 overflow (never read downstream)
#define NCQ 128     // column quads (4 columns per block)

#define PI_F 3.14159265358979323846f

// Swizzle for the per-wave FFT exchange region (512 float2): keeps all three
// access phases at the conflict-free b64 baseline (verified, absmax 0).
#define SW(r) ((r) ^ (((r) >> 4) & 0xF))
// Swizzle for the 512x8 transpose tile: A = 8c + (hh ^ ((c>>1)&7)).
#define TSW(c, hh) (((c) << 3) + ((hh) ^ (((c) >> 1) & 7)))

// DPP helpers (VALU-only cross-lane within 16-lane rows; no LDS pipe).
#define DPP_SHR(x, n) __builtin_amdgcn_update_dpp(0, (x), 0x110 + (n), 0xF, 0xF, true)
#define DPP_SHL1(x)   __builtin_amdgcn_update_dpp(0, (x), 0x101,       0xF, 0xF, true)

__device__ __forceinline__ float2 cadd(float2 a, float2 b){ return make_float2(a.x+b.x, a.y+b.y); }
__device__ __forceinline__ float2 csub(float2 a, float2 b){ return make_float2(a.x-b.x, a.y-b.y); }
__device__ __forceinline__ float2 cmul(float2 a, float2 b){
    return make_float2(a.x*b.x - a.y*b.y, a.x*b.y + a.y*b.x);
}

// 8-point DFT, y_r = sum_u a_u * w8^{ru} (forward, w8 = exp(-i pi/4)).
__device__ __forceinline__ void dft8(const float2* a, float2* y) {
    const float s2 = 0.70710678118654752440f;
    float2 t02a = cadd(a[0], a[4]), t02s = csub(a[0], a[4]);
    float2 t13a = cadd(a[2], a[6]), t13s = csub(a[2], a[6]);
    float2 E0 = cadd(t02a, t13a);
    float2 E2 = csub(t02a, t13a);
    float2 E1 = make_float2(t02s.x + t13s.y, t02s.y - t13s.x);
    float2 E3 = make_float2(t02s.x - t13s.y, t02s.y + t13s.x);
    float2 u02a = cadd(a[1], a[5]), u02s = csub(a[1], a[5]);
    float2 u13a = cadd(a[3], a[7]), u13s = csub(a[3], a[7]);
    float2 O0 = cadd(u02a, u13a);
    float2 O2 = csub(u02a, u13a);
    float2 O1 = make_float2(u02s.x + u13s.y, u02s.y - u13s.x);
    float2 O3 = make_float2(u02s.x - u13s.y, u02s.y + u13s.x);
    float2 wO1 = make_float2(s2 * (O1.x + O1.y), s2 * (O1.y - O1.x));
    float2 wO2 = make_float2(O2.y, -O2.x);
    float2 wO3 = make_float2(s2 * (O3.y - O3.x), -s2 * (O3.x + O3.y));
    y[0] = cadd(E0, O0);  y[4] = csub(E0, O0);
    y[1] = cadd(E1, wO1); y[5] = csub(E1, wO1);
    y[2] = cadd(E2, wO2); y[6] = csub(E2, wO2);
    y[3] = cadd(E3, wO3); y[7] = csub(E3, wO3);
}

__device__ __forceinline__ void twiddle8(float base, float2* w) {
    float s1, c1, s4, c4;
    __sincosf(base, &s1, &c1);
    __sincosf(4.0f * base, &s4, &c4);
    w[0] = make_float2(1.0f, 0.0f);
    w[1] = make_float2(c1, s1);
    w[2] = cmul(w[1], w[1]);
    w[3] = cmul(w[2], w[1]);
    w[4] = make_float2(c4, s4);
    w[5] = cmul(w[4], w[1]);
    w[6] = cmul(w[4], w[2]);
    w[7] = cmul(w[4], w[3]);
}

// Radix-8 Stockham, N=512 (verified): 2 LDS round trips, wave-local.
__device__ __forceinline__ void fft512_stage0_store(float2* rb, int lane, const float2* a) {
    float2 y[8]; dft8(a, y);
    float2 w[8]; twiddle8(-PI_F * (float)lane * (1.0f / 256.0f), w);
#pragma unroll
    for (int r = 0; r < 8; ++r) rb[SW(8 * lane + r)] = cmul(y[r], w[r]);
}

__device__ __forceinline__ void fft512_stage1(float2* rb, int lane) {
    float2 a[8];
#pragma unroll
    for (int u = 0; u < 8; ++u) a[u] = rb[SW(lane + 64 * u)];
    float2 y[8]; dft8(a, y);
    float2 w[8]; twiddle8(-PI_F * (float)(lane >> 3) * (1.0f / 32.0f), w);
    const int qb = (lane & 7) + ((lane >> 3) << 6);
#pragma unroll
    for (int r = 0; r < 8; ++r) rb[SW(qb + 8 * r)] = cmul(y[r], w[r]);
}

__device__ __forceinline__ void fft512_stage2(const float2* rb, int lane, float2* y) {
    float2 a[8];
#pragma unroll
    for (int u = 0; u < 8; ++u) a[u] = rb[SW(lane + 64 * u)];
    dft8(a, y);   // twiddle-free; y[r] = X[lane + 64r] (natural order)
}

// ---- Dual-FFT stages: two independent FFTs (fields A,B) interleaved at the
// instruction level in one wave. All LDS reads of both streams are issued
// before either dft8; the two dft8 dependency chains fill each other's VALU
// bubbles; the twiddle factors (lane-only dependent) are computed ONCE and
// shared by both streams.
__device__ __forceinline__ void dual_stage0(float2* rbA, float2* rbB, int lane,
                                            const float2* aA, const float2* aB) {
    float2 yA[8]; dft8(aA, yA);
    float2 yB[8]; dft8(aB, yB);
    float2 w[8]; twiddle8(-PI_F * (float)lane * (1.0f / 256.0f), w);
#pragma unroll
    for (int r = 0; r < 8; ++r) {
        rbA[SW(8 * lane + r)] = cmul(yA[r], w[r]);
        rbB[SW(8 * lane + r)] = cmul(yB[r], w[r]);
    }
}

__device__ __forceinline__ void dual_stage1(float2* rbA, float2* rbB, int lane) {
    float2 aA[8], aB[8];
#pragma unroll
    for (int u = 0; u < 8; ++u) aA[u] = rbA[SW(lane + 64 * u)];
#pragma unroll
    for (int u = 0; u < 8; ++u) aB[u] = rbB[SW(lane + 64 * u)];   // 16 reads in flight
    float2 yA[8]; dft8(aA, yA);
    float2 yB[8]; dft8(aB, yB);
    float2 w[8]; twiddle8(-PI_F * (float)(lane >> 3) * (1.0f / 32.0f), w);
    const int qb = (lane & 7) + ((lane >> 3) << 6);
#pragma unroll
    for (int r = 0; r < 8; ++r) {
        rbA[SW(qb + 8 * r)] = cmul(yA[r], w[r]);
        rbB[SW(qb + 8 * r)] = cmul(yB[r], w[r]);
    }
}

__device__ __forceinline__ void dual_stage2(const float2* rbA, const float2* rbB,
                                            int lane, float* pA, float* pB) {
    float2 aA[8], aB[8];
#pragma unroll
    for (int u = 0; u < 8; ++u) aA[u] = rbA[SW(lane + 64 * u)];
#pragma unroll
    for (int u = 0; u < 8; ++u) aB[u] = rbB[SW(lane + 64 * u)];
    float2 yA[8]; dft8(aA, yA);
    float2 yB[8]; dft8(aB, yB);
#pragma unroll
    for (int r = 0; r < 8; ++r) {
        pA[r] = yA[r].x * yA[r].x + yA[r].y * yA[r].y;
        pB[r] = yB[r].x * yB[r].x + yB[r].y * yB[r].y;
    }
}

// ---------------------------------------------------------------------------
// Row pass: unchanged (2.8 TB/s effective).
// ---------------------------------------------------------------------------
__global__ __launch_bounds__(512, 4)
void row_fft_kernel(const float2* __restrict__ z, const float2* __restrict__ t,
                    float2* __restrict__ fieldsT, int b0) {
    __shared__ float2 buf[8 * 512];   // 32 KiB: FFT regions, then transpose tile
    const int tid  = threadIdx.x;
    const int lane = tid & 63;
    const int g    = tid >> 6;
    const int bid  = blockIdx.x;
    const int hg   = bid & 63;
    const int lb   = bid >> 6;
    const int b    = b0 + lb;
    const int h    = (hg << 3) | g;
    const size_t rowOff = ((size_t)(b * HH + h)) * WW;

    const float2* tr = t + rowOff;
    const float2* zr = z + rowOff;
    float2 tv[8], zv[8];
#pragma unroll
    for (int u = 0; u < 8; ++u) tv[u] = tr[lane + 64 * u];
#pragma unroll
    for (int u = 0; u < 8; ++u) zv[u] = zr[lane + 64 * u];

    float2* rb = buf + (g << 9);
#pragma unroll
    for (int f = 0; f < 2; ++f) {
        float2 a[8];
        if (f == 0) {
#pragma unroll
            for (int u = 0; u < 8; ++u) a[u] = tv[u];
        } else {
#pragma unroll
            for (int u = 0; u < 8; ++u) a[u] = make_float2(zv[u].x - tv[u].x,
                                                           zv[u].y - tv[u].y);
        }
        fft512_stage0_store(rb, lane, a);
        __builtin_amdgcn_wave_barrier();
        fft512_stage1(rb, lane);
        __builtin_amdgcn_wave_barrier();
        float2 y[8];
        fft512_stage2(rb, lane, y);

        __syncthreads();   // all waves done reading their FFT regions
#pragma unroll
        for (int r = 0; r < 8; ++r) {
            int c = lane + (r << 6);
            buf[TSW(c, g)] = y[r];
        }
        __syncthreads();
        float2* outF = fieldsT + ((size_t)(lb * 2 + f) << 18);  // * 512*512
#pragma unroll
        for (int k = 0; k < 8; ++k) {
            int e  = tid + (k << 9);
            int c  = e >> 3;
            int hh = e & 7;
            outF[((size_t)c << 9) + (hg << 3) + hh] = buf[TSW(c, hh)];
        }
        __syncthreads();   // tile region free before next field's stage 0
    }
}

// ---------------------------------------------------------------------------
// Column pass, R6: 256-thread blocks (R5's occupancy win), each wave owns one
// column and BOTH fields, processed as two stage-interleaved FFTs through two
// private 4-KiB LDS regions. Shared twiddles + shared binning masks between
// the two value streams. Wave-private hists in the (freed) FFT regions; one
// __syncthreads; non-atomic coalesced partials flush (no memset, no global
// atomics). grid = CB*128, LDS 32 KiB, 4 blocks/CU.
// ---------------------------------------------------------------------------
__global__ __launch_bounds__(256, 4)
void col_fft_bin_kernel(const float2* __restrict__ fieldsT,
                        float* __restrict__ partials, int b0) {
    __shared__ float2 buf[4 * 2 * 512];   // 32 KiB: 4 waves x 2 regions
    const int tid  = threadIdx.x;
    const int lane = tid & 63;
    const int g    = tid >> 6;        // 0..3
    const int bid  = blockIdx.x;
    const int cq   = bid & (NCQ - 1); // column quad
    const int lb   = bid >> 7;
    const int b    = b0 + lb;
    const int c    = (cq << 2) | g;

    const float2* colA = fieldsT + (((size_t)(lb * 2 + 0) << 9) + c) * 512;  // field t
    const float2* colB = fieldsT + (((size_t)(lb * 2 + 1) << 9) + c) * 512;  // field z-t
    float2 aA[8], aB[8];
#pragma unroll
    for (int u = 0; u < 8; ++u) aA[u] = colA[lane + (u << 6)];
#pragma unroll
    for (int u = 0; u < 8; ++u) aB[u] = colB[lane + (u << 6)];  // 16 loads in flight

    float2* rbA = buf + (g << 10);
    float2* rbB = rbA + 512;

    dual_stage0(rbA, rbB, lane, aA, aB);
    __builtin_amdgcn_wave_barrier();
    dual_stage1(rbA, rbB, lane);
    __builtin_amdgcn_wave_barrier();
    float pA[8], pB[8];
    dual_stage2(rbA, rbB, lane, pA, pB);
    __builtin_amdgcn_wave_barrier();
    __asm__ volatile("" ::: "memory");   // stage2 reads complete before hist zeroing

    // Zero hists: histA = first 512 floats of rbA, histB = first 512 of rbB.
#pragma unroll
    for (int j = 0; j < 4; ++j) {
        rbA[lane + (j << 6)] = make_float2(0.0f, 0.0f);
        rbB[lane + (j << 6)] = make_float2(0.0f, 0.0f);
    }
    __builtin_amdgcn_wave_barrier();
    __asm__ volatile("" ::: "memory");

    float* histA = (float*)rbA;
    float* histB = (float*)rbB;
    const int dc = c - 256;
    const unsigned fc2i = (unsigned)(dc * dc);
    const int l15 = lane & 15;
#pragma unroll
    for (int r = 0; r < 8; ++r) {
        int k  = lane + (r << 6);
        int dk = k - 256;
        unsigned m = (unsigned)(dk * dk) + fc2i;   // 65536 * ellipse, exact
        // bin = #{ j in [1,511] : j^2 * 65536 <= 261121 * m }  (exact integer check)
        int bin = (int)(sqrtf((float)m) * (511.0f / 256.0f));
        unsigned long long rhs = 261121ull * (unsigned long long)m;  // 511^2 * m
        unsigned bp1 = (unsigned)(bin + 1);
        if (((unsigned long long)(bp1 * bp1) << 16) <= rhs) ++bin;
        else if (((unsigned long long)((unsigned)bin * (unsigned)bin) << 16) > rhs) --bin;
        bin = (m < 65536u) ? bin : 511;            // overflow shell -> bin 511 (dead)

        float v = pA[r];
        float w = pB[r];

        // Segmented inclusive scan over equal-bin runs (bins monotone in lane):
        // masks computed once, applied to both fields' values.
        int nb; bool take;
        nb = DPP_SHR(bin, 1); take = (l15 >= 1 && nb == bin);
        v += take ? __int_as_float(DPP_SHR(__float_as_int(v), 1)) : 0.0f;
        w += take ? __int_as_float(DPP_SHR(__float_as_int(w), 1)) : 0.0f;
        nb = DPP_SHR(bin, 2); take = (l15 >= 2 && nb == bin);
        v += take ? __int_as_float(DPP_SHR(__float_as_int(v), 2)) : 0.0f;
        w += take ? __int_as_float(DPP_SHR(__float_as_int(w), 2)) : 0.0f;
        nb = DPP_SHR(bin, 4); take = (l15 >= 4 && nb == bin);
        v += take ? __int_as_float(DPP_SHR(__float_as_int(v), 4)) : 0.0f;
        w += take ? __int_as_float(DPP_SHR(__float_as_int(w), 4)) : 0.0f;
        nb = DPP_SHR(bin, 8); take = (l15 >= 8 && nb == bin);
        v += take ? __int_as_float(DPP_SHR(__float_as_int(v), 8)) : 0.0f;
        w += take ? __int_as_float(DPP_SHR(__float_as_int(w), 8)) : 0.0f;

        int nxt = DPP_SHL1(bin);                   // bin of lane+1 within the row
        if (l15 == 15 || nxt != bin) {             // last lane of its run
            atomicAdd(&histA[bin], v);
            atomicAdd(&histB[bin], w);
        }
    }
    __syncthreads();                     // all wave-private hists final

    // Cross-wave sum (4 waves) + coalesced non-atomic flush of BOTH fields.
    const float* bufF = (const float*)buf;
    float sA0 = 0.0f, sA1 = 0.0f, sB0 = 0.0f, sB1 = 0.0f;
#pragma unroll
    for (int w = 0; w < 4; ++w) {
        const int base = w << 11;        // wave w region pair, float offset
        sA0 += bufF[base + tid];
        sA1 += bufF[base + 256 + tid];
        sB0 += bufF[base + 1024 + tid];
        sB1 += bufF[base + 1024 + 256 + tid];
    }
    float* dA = partials + ((size_t)(cq << 5) + (size_t)b) * NBINS;            // f=0 (ns)
    float* dB = partials + ((size_t)(cq << 5) + (size_t)(NBATCH + b)) * NBINS; // f=1 (es)
    dA[tid] = sA0; dA[tid + 256] = sA1;
    dB[tid] = sB0; dB[tid + 256] = sB1;
}

// ---------------------------------------------------------------------------
// Fold the 128 column-quad partials: bins[fl][bin] = sum_cq partials[cq][fl][bin].
// grid = 32 blocks (one per fl), block = 512.
// ---------------------------------------------------------------------------
__global__ __launch_bounds__(512)
void reduce_bins_kernel(const float* __restrict__ partials, float* __restrict__ bins) {
    const int tid = threadIdx.x;
    const int fl  = blockIdx.x;               // 0..31 (f*16+b)
    float s = 0.0f;
#pragma unroll 8
    for (int cq = 0; cq < NCQ; ++cq)
        s += partials[((size_t)(cq << 5) + fl) * NBINS + tid];
    bins[(size_t)fl * NBINS + tid] = s;
}

// ---------------------------------------------------------------------------
// Loss: single block reads the 64 KiB bins array.
// ---------------------------------------------------------------------------
__global__ __launch_bounds__(512)
void loss_kernel(const float* __restrict__ bins, float* __restrict__ outp) {
    __shared__ float red[512];
    const int tid = threadIdx.x;
    float acc = 0.0f;
    if (tid < 511) {
#pragma unroll 4
        for (int b = 0; b < NBATCH; ++b) {
            float ns = bins[((size_t)b) * NBINS + tid];
            float es = bins[((size_t)(NBATCH + b)) * NBINS + tid];
            acc += es / fmaxf(ns, 1e-8f);
        }
    }
    red[tid] = acc;
    __syncthreads();
    for (int s = 256; s > 0; s >>= 1) {
        if (tid < s) red[tid] += red[tid + s];
        __syncthreads();
    }
    if (tid == 0) outp[0] = red[0] * (1.0f / NBATCH);
}

// ---------------------------------------------------------------------------
extern "C" void kernel_launch(void* const* d_in, const int* in_sizes, int n_in,
                              void* d_out, int out_size, void* d_ws, size_t ws_size,
                              hipStream_t stream) {
    const float2* z = (const float2*)d_in[0];
    const float2* t = (const float2*)d_in[1];
    float* outp = (float*)d_out;

    const size_t partialsBytes = (size_t)NCQ * 2 * NBATCH * NBINS * sizeof(float); // 8 MiB
    const size_t binsBytes     = (size_t)2 * NBATCH * NBINS * sizeof(float);       // 64 KiB
    const size_t fixedBytes    = partialsBytes + binsBytes;
    const size_t fpb = (size_t)2 * HH * WW * sizeof(float2);                       // 4 MiB/batch

    int CB = 16;
    while (CB > 1 && fixedBytes + (size_t)CB * fpb > ws_size) CB >>= 1;

    float*  partials = (float*)d_ws;
    float*  bins     = (float*)((char*)d_ws + partialsBytes);
    float2* fieldsT  = (float2*)((char*)d_ws + fixedBytes);

    // No memset needed: every partials slot is written unconditionally
    // (all cq x all (f,b) covered across the CB passes).
    for (int b0 = 0; b0 < NBATCH; b0 += CB) {
        row_fft_kernel<<<CB * 64, 512, 0, stream>>>(z, t, fieldsT, b0);
        col_fft_bin_kernel<<<CB * NCQ, 256, 0, stream>>>(fieldsT, partials, b0);
    }
    reduce_bins_kernel<<<32, 512, 0, stream>>>(partials, bins);
    loss_kernel<<<1, 512, 0, stream>>>(bins, outp);
}

// Round 7
// 157.728 us; speedup vs baseline: 1.0459x; 1.0459x over previous
//
#include <hip/hip_runtime.h>

#define HH 512
#define WW 512
#define NBATCH 16
#define NBINS 512   // 511 real shells + 1 overflow (never read downstream)
#define NCQ 128     // column quads (4 columns per col block)

#define PI_F 3.14159265358979323846f

// Swizzle for the per-wave FFT exchange region (512 float2): keeps all three
// access phases at the conflict-free b64 baseline (verified, absmax 0).
#define SW(r) ((r) ^ (((r) >> 4) & 0xF))
// Swizzle for the 512x8 transpose tile: A = 8c + (hh ^ ((c>>1)&7)).
#define TSW(c, hh) (((c) << 3) + ((hh) ^ (((c) >> 1) & 7)))

// DPP helpers (VALU-only cross-lane within 16-lane rows; no LDS pipe).
#define DPP_SHR(x, n) __builtin_amdgcn_update_dpp(0, (x), 0x110 + (n), 0xF, 0xF, true)
#define DPP_SHL1(x)   __builtin_amdgcn_update_dpp(0, (x), 0x101,       0xF, 0xF, true)

__device__ __forceinline__ float2 cadd(float2 a, float2 b){ return make_float2(a.x+b.x, a.y+b.y); }
__device__ __forceinline__ float2 csub(float2 a, float2 b){ return make_float2(a.x-b.x, a.y-b.y); }
__device__ __forceinline__ float2 cmul(float2 a, float2 b){
    return make_float2(a.x*b.x - a.y*b.y, a.x*b.y + a.y*b.x);
}

// 8-point DFT, y_r = sum_u a_u * w8^{ru} (forward, w8 = exp(-i pi/4)).
__device__ __forceinline__ void dft8(const float2* a, float2* y) {
    const float s2 = 0.70710678118654752440f;
    float2 t02a = cadd(a[0], a[4]), t02s = csub(a[0], a[4]);
    float2 t13a = cadd(a[2], a[6]), t13s = csub(a[2], a[6]);
    float2 E0 = cadd(t02a, t13a);
    float2 E2 = csub(t02a, t13a);
    float2 E1 = make_float2(t02s.x + t13s.y, t02s.y - t13s.x);
    float2 E3 = make_float2(t02s.x - t13s.y, t02s.y + t13s.x);
    float2 u02a = cadd(a[1], a[5]), u02s = csub(a[1], a[5]);
    float2 u13a = cadd(a[3], a[7]), u13s = csub(a[3], a[7]);
    float2 O0 = cadd(u02a, u13a);
    float2 O2 = csub(u02a, u13a);
    float2 O1 = make_float2(u02s.x + u13s.y, u02s.y - u13s.x);
    float2 O3 = make_float2(u02s.x - u13s.y, u02s.y + u13s.x);
    float2 wO1 = make_float2(s2 * (O1.x + O1.y), s2 * (O1.y - O1.x));
    float2 wO2 = make_float2(O2.y, -O2.x);
    float2 wO3 = make_float2(s2 * (O3.y - O3.x), -s2 * (O3.x + O3.y));
    y[0] = cadd(E0, O0);  y[4] = csub(E0, O0);
    y[1] = cadd(E1, wO1); y[5] = csub(E1, wO1);
    y[2] = cadd(E2, wO2); y[6] = csub(E2, wO2);
    y[3] = cadd(E3, wO3); y[7] = csub(E3, wO3);
}

__device__ __forceinline__ void twiddle8(float base, float2* w) {
    float s1, c1, s4, c4;
    __sincosf(base, &s1, &c1);
    __sincosf(4.0f * base, &s4, &c4);
    w[0] = make_float2(1.0f, 0.0f);
    w[1] = make_float2(c1, s1);
    w[2] = cmul(w[1], w[1]);
    w[3] = cmul(w[2], w[1]);
    w[4] = make_float2(c4, s4);
    w[5] = cmul(w[4], w[1]);
    w[6] = cmul(w[4], w[2]);
    w[7] = cmul(w[4], w[3]);
}

// Radix-8 Stockham, N=512 (verified): 2 LDS round trips, wave-local.
__device__ __forceinline__ void fft512_stage0_store(float2* rb, int lane, const float2* a) {
    float2 y[8]; dft8(a, y);
    float2 w[8]; twiddle8(-PI_F * (float)lane * (1.0f / 256.0f), w);
#pragma unroll
    for (int r = 0; r < 8; ++r) rb[SW(8 * lane + r)] = cmul(y[r], w[r]);
}

__device__ __forceinline__ void fft512_stage1(float2* rb, int lane) {
    float2 a[8];
#pragma unroll
    for (int u = 0; u < 8; ++u) a[u] = rb[SW(lane + 64 * u)];
    float2 y[8]; dft8(a, y);
    float2 w[8]; twiddle8(-PI_F * (float)(lane >> 3) * (1.0f / 32.0f), w);
    const int qb = (lane & 7) + ((lane >> 3) << 6);
#pragma unroll
    for (int r = 0; r < 8; ++r) rb[SW(qb + 8 * r)] = cmul(y[r], w[r]);
}

__device__ __forceinline__ void fft512_stage2(const float2* rb, int lane, float2* y) {
    float2 a[8];
#pragma unroll
    for (int u = 0; u < 8; ++u) a[u] = rb[SW(lane + 64 * u)];
    dft8(a, y);   // twiddle-free; y[r] = X[lane + 64r] (natural order)
}

// ---------------------------------------------------------------------------
// Row pass. R7 change: fieldsT uses a column-PAIR-interleaved layout
//   element (c, h)  ->  ((c>>1)<<10) + (h<<1) + (c&1)     [float2 units]
// so the transpose store emits 16 consecutive float2 (= one full 128 B cache
// line) per column-pair per block: every line of the intermediate is written
// WHOLE by a single block (bytes [hg*128,(hg+1)*128) of each pair-column
// belong exactly to block hg). This eliminates the cross-XCD partial-line
// (64 B sector) writes of the old layout, which R0-R6 never varied and which
// are the last asymmetry vs the 3x-faster z/t read stream.
// ---------------------------------------------------------------------------
__global__ __launch_bounds__(512, 4)
void row_fft_kernel(const float2* __restrict__ z, const float2* __restrict__ t,
                    float2* __restrict__ fieldsT, int b0) {
    __shared__ float2 buf[8 * 512];   // 32 KiB: FFT regions, then transpose tile
    const int tid  = threadIdx.x;
    const int lane = tid & 63;
    const int g    = tid >> 6;
    const int bid  = blockIdx.x;
    const int hg   = bid & 63;
    const int lb   = bid >> 6;
    const int b    = b0 + lb;
    const int h    = (hg << 3) | g;
    const size_t rowOff = ((size_t)(b * HH + h)) * WW;

    const float2* tr = t + rowOff;
    const float2* zr = z + rowOff;
    float2 tv[8], zv[8];
#pragma unroll
    for (int u = 0; u < 8; ++u) tv[u] = tr[lane + 64 * u];
#pragma unroll
    for (int u = 0; u < 8; ++u) zv[u] = zr[lane + 64 * u];

    float2* rb = buf + (g << 9);
#pragma unroll
    for (int f = 0; f < 2; ++f) {
        float2 a[8];
        if (f == 0) {
#pragma unroll
            for (int u = 0; u < 8; ++u) a[u] = tv[u];
        } else {
#pragma unroll
            for (int u = 0; u < 8; ++u) a[u] = make_float2(zv[u].x - tv[u].x,
                                                           zv[u].y - tv[u].y);
        }
        fft512_stage0_store(rb, lane, a);
        __builtin_amdgcn_wave_barrier();
        fft512_stage1(rb, lane);
        __builtin_amdgcn_wave_barrier();
        float2 y[8];
        fft512_stage2(rb, lane, y);

        __syncthreads();   // all waves done reading their FFT regions
#pragma unroll
        for (int r = 0; r < 8; ++r) {
            int c = lane + (r << 6);
            buf[TSW(c, g)] = y[r];
        }
        __syncthreads();
        float2* outF = fieldsT + ((size_t)(lb * 2 + f) << 18);  // * 512*512
#pragma unroll
        for (int k = 0; k < 8; ++k) {
            int e  = tid + (k << 9);
            int c  = e >> 3;
            int hh = e & 7;
            int hr = (hg << 3) | hh;
            // pair-interleaved: full 128B line per c-pair per block
            outF[((size_t)(c >> 1) << 10) + (hr << 1) + (c & 1)] = buf[TSW(c, hh)];
        }
        __syncthreads();   // tile region free before next field's stage 0
    }
}

// ---------------------------------------------------------------------------
// Column pass, R7: R5's fastest-known geometry (256 thr = 4 waves, one
// (column, field) per wave, 16 KiB LDS, 8 blocks/CU) reading the pair-
// interleaved layout at stride-2 float2; the complementary 8 B of each line
// is consumed by the sibling wave of the same block (L1/L2 hit, no
// over-fetch). Binning identical to R2 (verified): exact integer shell index
// + DPP segmented scan + wave-private LDS hist. Flush: non-atomic coalesced
// partials (no memset, no global atomics). grid = CB*2*128.
// ---------------------------------------------------------------------------
__global__ __launch_bounds__(256, 8)
void col_fft_bin_kernel(const float2* __restrict__ fieldsT,
                        float* __restrict__ partials, int b0) {
    __shared__ float2 buf[4 * 512];   // 16 KiB: 4 wave FFT regions (reused as hists)
    const int tid  = threadIdx.x;
    const int lane = tid & 63;
    const int g    = tid >> 6;        // 0..3
    const int bid  = blockIdx.x;
    const int cq   = bid & (NCQ - 1); // column quad
    const int f    = (bid >> 7) & 1;
    const int lb   = bid >> 8;
    const int b    = b0 + lb;
    const int c    = (cq << 2) | g;

    // element (c,h) at ((c>>1)<<10) + (h<<1) + (c&1)
    const float2* colT = fieldsT + ((size_t)(lb * 2 + f) << 18)
                                 + ((size_t)(c >> 1) << 10) + (c & 1);
    float2 a[8];
#pragma unroll
    for (int u = 0; u < 8; ++u) a[u] = colT[(lane + (u << 6)) << 1];

    float2* rb = buf + (g << 9);
    fft512_stage0_store(rb, lane, a);
    __builtin_amdgcn_wave_barrier();
    fft512_stage1(rb, lane);
    __builtin_amdgcn_wave_barrier();
    float2 y[8];
    fft512_stage2(rb, lane, y);
    __builtin_amdgcn_wave_barrier();
    __asm__ volatile("" ::: "memory");   // stage2 reads complete before hist zeroing

    // Zero the wave's private 512-float hist (first 256 float2 of its region).
#pragma unroll
    for (int j = 0; j < 4; ++j) rb[lane + (j << 6)] = make_float2(0.0f, 0.0f);
    __builtin_amdgcn_wave_barrier();
    __asm__ volatile("" ::: "memory");

    float* histw = (float*)rb;           // 512 wave-private bins
    const int dc = c - 256;
    const unsigned fc2i = (unsigned)(dc * dc);
    const int l15 = lane & 15;
#pragma unroll
    for (int r = 0; r < 8; ++r) {
        int k  = lane + (r << 6);
        int dk = k - 256;
        unsigned m = (unsigned)(dk * dk) + fc2i;   // 65536 * ellipse, exact
        // bin = #{ j in [1,511] : j^2 * 65536 <= 261121 * m }  (exact integer check)
        int bin = (int)(sqrtf((float)m) * (511.0f / 256.0f));
        unsigned long long rhs = 261121ull * (unsigned long long)m;  // 511^2 * m
        unsigned bp1 = (unsigned)(bin + 1);
        if (((unsigned long long)(bp1 * bp1) << 16) <= rhs) ++bin;
        else if (((unsigned long long)((unsigned)bin * (unsigned)bin) << 16) > rhs) --bin;
        bin = (m < 65536u) ? bin : 511;            // overflow shell -> bin 511 (dead)

        float v = y[r].x * y[r].x + y[r].y * y[r].y;

        // Segmented inclusive scan over equal-bin runs (bins monotone in lane),
        // VALU-only via DPP row_shr within each 16-lane row.
        int nb; float nv;
        nb = DPP_SHR(bin, 1);
        nv = __int_as_float(DPP_SHR(__float_as_int(v), 1));
        v += (l15 >= 1 && nb == bin) ? nv : 0.0f;
        nb = DPP_SHR(bin, 2);
        nv = __int_as_float(DPP_SHR(__float_as_int(v), 2));
        v += (l15 >= 2 && nb == bin) ? nv : 0.0f;
        nb = DPP_SHR(bin, 4);
        nv = __int_as_float(DPP_SHR(__float_as_int(v), 4));
        v += (l15 >= 4 && nb == bin) ? nv : 0.0f;
        nb = DPP_SHR(bin, 8);
        nv = __int_as_float(DPP_SHR(__float_as_int(v), 8));
        v += (l15 >= 8 && nb == bin) ? nv : 0.0f;

        int nxt = DPP_SHL1(bin);                   // bin of lane+1 within the row
        if (l15 == 15 || nxt != bin)               // last lane of its run
            atomicAdd(&histw[bin], v);
    }
    __syncthreads();                     // all 4 wave-private hists final

    // Cross-wave sum (4 regions, fixed order) + coalesced non-atomic flush.
    const float* bufF = (const float*)buf;
    float s0 = 0.0f, s1 = 0.0f;
#pragma unroll
    for (int w = 0; w < 4; ++w) {
        s0 += bufF[(w << 10) + tid];
        s1 += bufF[(w << 10) + 256 + tid];
    }
    const int fl = f * NBATCH + b;
    float* dst = partials + ((size_t)(cq << 5) + (size_t)fl) * NBINS;
    dst[tid] = s0;
    dst[tid + 256] = s1;
}

// ---------------------------------------------------------------------------
// Fold the 128 column-quad partials: bins[fl][bin] = sum_cq partials[cq][fl][bin].
// grid = 32 blocks (one per fl), block = 512.
// ---------------------------------------------------------------------------
__global__ __launch_bounds__(512)
void reduce_bins_kernel(const float* __restrict__ partials, float* __restrict__ bins) {
    const int tid = threadIdx.x;
    const int fl  = blockIdx.x;               // 0..31 (f*16+b)
    float s = 0.0f;
#pragma unroll 8
    for (int cq = 0; cq < NCQ; ++cq)
        s += partials[((size_t)(cq << 5) + fl) * NBINS + tid];
    bins[(size_t)fl * NBINS + tid] = s;
}

// ---------------------------------------------------------------------------
// Loss: single block reads the 64 KiB bins array.
// ---------------------------------------------------------------------------
__global__ __launch_bounds__(512)
void loss_kernel(const float* __restrict__ bins, float* __restrict__ outp) {
    __shared__ float red[512];
    const int tid = threadIdx.x;
    float acc = 0.0f;
    if (tid < 511) {
#pragma unroll 4
        for (int b = 0; b < NBATCH; ++b) {
            float ns = bins[((size_t)b) * NBINS + tid];
            float es = bins[((size_t)(NBATCH + b)) * NBINS + tid];
            acc += es / fmaxf(ns, 1e-8f);
        }
    }
    red[tid] = acc;
    __syncthreads();
    for (int s = 256; s > 0; s >>= 1) {
        if (tid < s) red[tid] += red[tid + s];
        __syncthreads();
    }
    if (tid == 0) outp[0] = red[0] * (1.0f / NBATCH);
}

// ---------------------------------------------------------------------------
extern "C" void kernel_launch(void* const* d_in, const int* in_sizes, int n_in,
                              void* d_out, int out_size, void* d_ws, size_t ws_size,
                              hipStream_t stream) {
    const float2* z = (const float2*)d_in[0];
    const float2* t = (const float2*)d_in[1];
    float* outp = (float*)d_out;

    const size_t partialsBytes = (size_t)NCQ * 2 * NBATCH * NBINS * sizeof(float); // 8 MiB
    const size_t binsBytes     = (size_t)2 * NBATCH * NBINS * sizeof(float);       // 64 KiB
    const size_t fixedBytes    = partialsBytes + binsBytes;
    const size_t fpb = (size_t)2 * HH * WW * sizeof(float2);                       // 4 MiB/batch

    int CB = 16;
    while (CB > 1 && fixedBytes + (size_t)CB * fpb > ws_size) CB >>= 1;

    float*  partials = (float*)d_ws;
    float*  bins     = (float*)((char*)d_ws + partialsBytes);
    float2* fieldsT  = (float2*)((char*)d_ws + fixedBytes);

    // No memset needed: every partials slot is written unconditionally
    // (all cq x all (f,b) covered across the CB passes).
    for (int b0 = 0; b0 < NBATCH; b0 += CB) {
        row_fft_kernel<<<CB * 64, 512, 0, stream>>>(z, t, fieldsT, b0);
        col_fft_bin_kernel<<<CB * 2 * NCQ, 256, 0, stream>>>(fieldsT, partials, b0);
    }
    reduce_bins_kernel<<<32, 512, 0, stream>>>(partials, bins);
    loss_kernel<<<1, 512, 0, stream>>>(bins, outp);
}